// Round 1
// 504.125 us; speedup vs baseline: 1.0231x; 1.0231x over previous
//
#include <hip/hip_runtime.h>

#define HH 540
#define WW 960
#define NB 16
#define NCH 34                        // ceil(540/16) row-chunks of 16
#define NPB (HH * WW)                 // 518400 rows per batch
#define NF  (NPB * 5)                 // 2,592,000 floats of rect per batch
static const float STRIDE_F = (float)(1919.0 / 959.0);
#define THR 0.6f

// ---------------- kernel 1: per-(column, 16-row-chunk) accepted counts -----------
// grid (60, 34, 16), block 256 = 16 cols x 16 rows. One ballot, direct store.
// No atomics, no zero pass needed.
__global__ __launch_bounds__(256) void k_cnt(const float* __restrict__ cls,
                                             int* __restrict__ cnt) {
    __shared__ int wcnt_s[4][16];
    int t = threadIdx.x;
    int w_l = t & 15;                 // column within block
    int h_l = t >> 4;                 // row within chunk
    int wave = t >> 6;
    int h_lw = h_l & 3;               // row within wave
    int hc = blockIdx.y;
    int b = blockIdx.z;
    int w = blockIdx.x * 16 + w_l;
    int h = hc * 16 + h_l;
    bool valid = h < HH;
    const float* cbase = cls + (size_t)b * NPB * 2;
    float p = valid ? cbase[(size_t)(h * WW + w) * 2 + 1] : 0.0f;
    bool m = valid && (p >= THR);
    unsigned long long bal = __ballot(m);
    unsigned long long colmask = 0x0001000100010001ULL << w_l;
    int wc = __popcll(bal & colmask);
    if (h_lw == 0) wcnt_s[wave][w_l] = wc;
    __syncthreads();
    if (t < 16) {
        int tot = wcnt_s[0][t] + wcnt_s[1][t] + wcnt_s[2][t] + wcnt_s[3][t];
        cnt[((size_t)b * NCH + hc) * WW + blockIdx.x * 16 + t] = tot;
    }
}

// ---------------- kernel 2: per-batch column scan + per-chunk absolute bases -----
// One block of 1024 per batch. Column totals -> exclusive scan over w (the stable
// order is w-major) -> replay chunks writing abase[b][hc][w]. All coalesced.
__global__ void k_scan(const int* __restrict__ cnt, int* __restrict__ abase,
                       int* __restrict__ totals, const float* __restrict__ img,
                       float* __restrict__ out_img) {
    __shared__ int s[1024];
    int b = blockIdx.x;
    int t = threadIdx.x;
    const int* c = cnt + (size_t)b * NCH * WW;
    int tot = 0;
    if (t < WW) {
        for (int hc = 0; hc < NCH; ++hc) tot += c[hc * WW + t];
    }
    s[t] = tot;
    __syncthreads();
    for (int d = 1; d < 1024; d <<= 1) {         // Hillis-Steele inclusive scan
        int x = s[t];
        int y = (t >= d) ? s[t - d] : 0;
        __syncthreads();
        s[t] = x + y;
        __syncthreads();
    }
    if (t < WW) {
        int run = s[t] - tot;                    // exclusive column base
        int* ab = abase + (size_t)b * NCH * WW;
        for (int hc = 0; hc < NCH; ++hc) {       // intra-column chunk prefix
            ab[hc * WW + t] = run;
            run += c[hc * WW + t];
        }
    }
    if (t == 0) totals[b] = s[1023];
    if (t < 2) out_img[b * 2 + t] = img[b * 2 + t] + 1.0f;
}

// ---------------- kernel 3: fully parallel compact (one chunk per block) ---------
// grid (60, 34, 16): no serial loop, no running carry — base comes from abase.
__global__ __launch_bounds__(256) void k_compact(const float* __restrict__ cls,
                                                 const float4* __restrict__ roi,
                                                 const int* __restrict__ abase,
                                                 float* __restrict__ out1,
                                                 float* __restrict__ out2) {
    __shared__ int wcnt_s[4][16];
    __shared__ float rows_s[16 * 85];            // 16 cols x 16 rows x 5, pad 85
    int t = threadIdx.x;
    int w_l = t & 15;
    int h_l = t >> 4;
    int wave = t >> 6;
    int h_lw = h_l & 3;
    int hc = blockIdx.y;
    int b = blockIdx.z;
    int w = blockIdx.x * 16 + w_l;
    int h = hc * 16 + h_l;
    const float*  cbase = cls + (size_t)b * NPB * 2;
    const float4* rbase = roi + (size_t)b * NPB;

    bool valid = h < HH;
    float p = valid ? cbase[(size_t)(h * WW + w) * 2 + 1] : 0.0f;
    bool m = valid && (p >= THR);

    unsigned long long bal = __ballot(m);
    unsigned long long colmask = 0x0001000100010001ULL << w_l;
    int off = __popcll(bal & colmask & ((1ULL << (h_lw * 16)) - 1ULL));
    int wc  = __popcll(bal & colmask);
    if (h_lw == 0) wcnt_s[wave][w_l] = wc;
    __syncthreads();
#pragma unroll
    for (int v = 0; v < 4; ++v) {
        int x = wcnt_s[v][w_l];
        if (v < wave) off += x;
    }

    if (m) {
        float4 r = rbase[h * WW + w];
        float sxw = truncf(STRIDE_F * (float)w);
        float exw = truncf(STRIDE_F * (float)w + 11.0f);
        float sy  = truncf(STRIDE_F * (float)h);
        float ey  = truncf(STRIDE_F * (float)h + 11.0f);
        float x1 = sxw + r.x * 12.0f;
        float y1 = sy  + r.y * 12.0f;
        float x2 = exw + r.z * 12.0f;
        float y2 = ey  + r.w * 12.0f;
        float wd = x2 - x1;
        float hd = y2 - y1;
        float l  = fmaxf(wd, hd);
        float nx1 = x1 + wd * 0.5f - l * 0.5f;
        float ny1 = y1 + hd * 0.5f - l * 0.5f;
        int sb = w_l * 85 + off * 5;
        rows_s[sb + 0] = nx1;
        rows_s[sb + 1] = ny1;
        rows_s[sb + 2] = nx1 + l;
        rows_s[sb + 3] = ny1 + l;
        rows_s[sb + 4] = p;
    }
    __syncthreads();

    // flush: column fc = t/16, dword lane fj = t%16 (consecutive tid -> consecutive addr)
    int fc = h_l;
    int fj = w_l;
    int tot_f = wcnt_s[0][fc] + wcnt_s[1][fc] + wcnt_s[2][fc] + wcnt_s[3][fc];
    int cb_f = abase[((size_t)b * NCH + hc) * WW + blockIdx.x * 16 + fc];
    int nd = tot_f * 5;
    size_t gb = ((size_t)b * NPB + (size_t)cb_f) * 5;
    for (int d = fj; d < nd; d += 16) {
        float val = rows_s[fc * 85 + d];
        out1[gb + d] = val;
        out2[gb + d] = val;
    }
}

// ---------------- kernel 4: zero the tail rows [K, NPB) ----------------
__global__ void k_ztail(const int* __restrict__ totals, float* __restrict__ out1,
                        float* __restrict__ out2) {
    int b = blockIdx.y;
    int K5 = totals[b] * 5;
    int chunk = blockIdx.x * blockDim.x + threadIdx.x;   // float4 chunk idx in batch
    int f0 = chunk * 4;
    if (f0 >= NF) return;
    size_t base = (size_t)b * NF;
    if (f0 >= K5) {
        float4 z = make_float4(0.f, 0.f, 0.f, 0.f);
        *(float4*)(out1 + base + f0) = z;
        *(float4*)(out2 + base + f0) = z;
    } else if (f0 + 4 > K5) {
        for (int j = K5; j < f0 + 4; ++j) {
            out1[base + j] = 0.0f;
            out2[base + j] = 0.0f;
        }
    }
}

extern "C" void kernel_launch(void* const* d_in, const int* in_sizes, int n_in,
                              void* d_out, int out_size, void* d_ws, size_t ws_size,
                              hipStream_t stream) {
    const float* cls = (const float*)d_in[0];   // [16,540,960,2]
    const float* roi = (const float*)d_in[1];   // [16,540,960,4]
    const float* img = (const float*)d_in[2];   // [16,2]

    float* out1 = (float*)d_out;                     // rect copy 1
    float* out2 = out1 + (size_t)NB * NF;            // rect copy 2
    float* outimg = out2 + (size_t)NB * NF;          // img + 1

    int* cnt    = (int*)d_ws;                        // [16][34][960]
    int* abase  = cnt + (size_t)NB * NCH * WW;       // [16][34][960]
    int* totals = abase + (size_t)NB * NCH * WW;     // [16]

    k_cnt<<<dim3(60, NCH, NB), dim3(256), 0, stream>>>(cls, cnt);
    k_scan<<<dim3(NB), dim3(1024), 0, stream>>>(cnt, abase, totals, img, outimg);
    k_compact<<<dim3(60, NCH, NB), dim3(256), 0, stream>>>(cls, (const float4*)roi,
                                                           abase, out1, out2);
    k_ztail<<<dim3((NF / 4 + 255) / 256, NB), dim3(256), 0, stream>>>(totals, out1, out2);
}

// Round 3
// 503.741 us; speedup vs baseline: 1.0239x; 1.0008x over previous
//
#include <hip/hip_runtime.h>

#define HH 540
#define WW 960
#define NB 16
#define NCH 34                        // ceil(540/16) row-chunks of 16
#define NPB (HH * WW)                 // 518400 rows per batch
#define NF  (NPB * 5)                 // 2,592,000 floats of rect per batch
static const float STRIDE_F = (float)(1919.0 / 959.0);
#define THR 0.6f

// ---------------- kernel 1: per-(column, 16-row-chunk) accepted counts -----------
// grid (30, 34, 16), block 256 = 16 w-pairs x 16 rows; float4 load = 2 pixels.
// Two ballots give counts for 32 columns per block. No atomics.
__global__ __launch_bounds__(256) void k_cnt(const float4* __restrict__ cls4,
                                             int* __restrict__ cnt) {
    __shared__ int wcnt_s[4][32];
    int t = threadIdx.x;
    int wp = t & 15;                  // w-pair within block
    int h_l = t >> 4;                 // row within chunk
    int wave = t >> 6;
    int h_lw = h_l & 3;               // row within wave
    int hc = blockIdx.y;
    int b = blockIdx.z;
    int w0 = blockIdx.x * 32 + wp * 2;
    int h = hc * 16 + h_l;
    bool valid = h < HH;
    bool c0 = false, c1 = false;
    if (valid) {
        float4 v = cls4[(size_t)b * (NPB / 2) + (((size_t)h * WW + w0) >> 1)];
        c0 = v.y >= THR;
        c1 = v.w >= THR;
    }
    unsigned long long bal0 = __ballot(c0);
    unsigned long long bal1 = __ballot(c1);
    unsigned long long colmask = 0x0001000100010001ULL << wp;
    if (h_lw == 0) {
        wcnt_s[wave][wp * 2]     = __popcll(bal0 & colmask);
        wcnt_s[wave][wp * 2 + 1] = __popcll(bal1 & colmask);
    }
    __syncthreads();
    if (t < 32) {
        int tot = wcnt_s[0][t] + wcnt_s[1][t] + wcnt_s[2][t] + wcnt_s[3][t];
        cnt[((size_t)b * NCH + hc) * WW + blockIdx.x * 32 + t] = tot;
    }
}

// ---------------- kernel 2: per-batch column scan + per-chunk absolute bases -----
// Wave-shfl scan: 2 barriers instead of 20. One block of 1024 per batch.
__global__ void k_scan(const int* __restrict__ cnt, int* __restrict__ abase,
                       int* __restrict__ totals, const float* __restrict__ img,
                       float* __restrict__ out_img) {
    __shared__ int wsum[16];
    __shared__ int wexc[16];
    int b = blockIdx.x;
    int t = threadIdx.x;
    int lane = t & 63;
    int wv = t >> 6;
    const int* c = cnt + (size_t)b * NCH * WW;
    int tot = 0;
    if (t < WW) {
        for (int hc = 0; hc < NCH; ++hc) tot += c[hc * WW + t];
    }
    int x = tot;                                  // wave-local inclusive scan
#pragma unroll
    for (int d = 1; d < 64; d <<= 1) {
        int y = __shfl_up(x, d);
        if (lane >= d) x += y;
    }
    if (lane == 63) wsum[wv] = x;
    __syncthreads();
    if (wv == 0) {                                // scan the 16 wave sums
        int s = (lane < 16) ? wsum[lane] : 0;
#pragma unroll
        for (int d = 1; d < 16; d <<= 1) {
            int y = __shfl_up(s, d);
            if (lane >= d) s += y;
        }
        if (lane < 16) wexc[lane] = s - wsum[lane];
    }
    __syncthreads();
    int incl = x + wexc[wv];
    if (t < WW) {
        int run = incl - tot;                     // exclusive column base
        int* ab = abase + (size_t)b * NCH * WW;
        for (int hc = 0; hc < NCH; ++hc) {        // intra-column chunk prefix
            ab[hc * WW + t] = run;
            run += c[hc * WW + t];
        }
    }
    if (t == 1023) totals[b] = incl;              // full-batch total
    if (t < 2) out_img[b * 2 + t] = img[b * 2 + t] + 1.0f;
}

// ---------------- kernel 3: fully parallel compact, float4 flush -----------------
__global__ __launch_bounds__(256) void k_compact(const float* __restrict__ cls,
                                                 const float4* __restrict__ roi,
                                                 const int* __restrict__ abase,
                                                 float* __restrict__ out1,
                                                 float* __restrict__ out2) {
    __shared__ int wcnt_s[4][16];
    __shared__ float rows_s[16 * 85];            // 16 cols x 16 rows x 5, pad 85
    int t = threadIdx.x;
    int w_l = t & 15;
    int h_l = t >> 4;
    int wave = t >> 6;
    int h_lw = h_l & 3;
    int hc = blockIdx.y;
    int b = blockIdx.z;
    int w = blockIdx.x * 16 + w_l;
    int h = hc * 16 + h_l;
    const float*  cbase = cls + (size_t)b * NPB * 2;
    const float4* rbase = roi + (size_t)b * NPB;

    bool valid = h < HH;
    float p = valid ? cbase[(size_t)(h * WW + w) * 2 + 1] : 0.0f;
    bool m = valid && (p >= THR);

    unsigned long long bal = __ballot(m);
    unsigned long long colmask = 0x0001000100010001ULL << w_l;
    int off = __popcll(bal & colmask & ((1ULL << (h_lw * 16)) - 1ULL));
    int wc  = __popcll(bal & colmask);
    if (h_lw == 0) wcnt_s[wave][w_l] = wc;
    __syncthreads();
#pragma unroll
    for (int v = 0; v < 4; ++v) {
        int x = wcnt_s[v][w_l];
        if (v < wave) off += x;
    }

    if (m) {
        float4 r = rbase[h * WW + w];
        float sxw = truncf(STRIDE_F * (float)w);
        float exw = truncf(STRIDE_F * (float)w + 11.0f);
        float sy  = truncf(STRIDE_F * (float)h);
        float ey  = truncf(STRIDE_F * (float)h + 11.0f);
        float x1 = sxw + r.x * 12.0f;
        float y1 = sy  + r.y * 12.0f;
        float x2 = exw + r.z * 12.0f;
        float y2 = ey  + r.w * 12.0f;
        float wd = x2 - x1;
        float hd = y2 - y1;
        float l  = fmaxf(wd, hd);
        float nx1 = x1 + wd * 0.5f - l * 0.5f;
        float ny1 = y1 + hd * 0.5f - l * 0.5f;
        int sb = w_l * 85 + off * 5;
        rows_s[sb + 0] = nx1;
        rows_s[sb + 1] = ny1;
        rows_s[sb + 2] = nx1 + l;
        rows_s[sb + 3] = ny1 + l;
        rows_s[sb + 4] = p;
    }
    __syncthreads();

    // flush: column fc = t/16, lane fj = t%16. Align to 16 B, body = float4 stores.
    int fc = h_l;
    int fj = w_l;
    int tot_f = wcnt_s[0][fc] + wcnt_s[1][fc] + wcnt_s[2][fc] + wcnt_s[3][fc];
    int cb_f = abase[((size_t)b * NCH + hc) * WW + blockIdx.x * 16 + fc];
    int nd = tot_f * 5;
    size_t gb = ((size_t)b * NPB + (size_t)cb_f) * 5;
    const float* src = rows_s + fc * 85;

    int head = (int)((4 - (gb & 3)) & 3);        // dwords to 16-B boundary
    if (head > nd) head = nd;
    if (fj < head) {
        float v = src[fj];
        out1[gb + fj] = v;
        out2[gb + fj] = v;
    }
    int nb4 = (nd - head) >> 2;                  // aligned float4 body count (<=20)
    for (int i4 = fj; i4 < nb4; i4 += 16) {
        int d0 = head + i4 * 4;
        float4 v = make_float4(src[d0], src[d0 + 1], src[d0 + 2], src[d0 + 3]);
        *(float4*)(out1 + gb + d0) = v;
        *(float4*)(out2 + gb + d0) = v;
    }
    int t0 = head + nb4 * 4;
    int d = t0 + fj;
    if (d < nd) {                                // tail (<=3 dwords)
        float v = src[d];
        out1[gb + d] = v;
        out2[gb + d] = v;
    }
}

// ---------------- kernel 4: zero the tail rows [K, NPB) ----------------
__global__ void k_ztail(const int* __restrict__ totals, float* __restrict__ out1,
                        float* __restrict__ out2) {
    int b = blockIdx.y;
    int K5 = totals[b] * 5;
    int chunk = blockIdx.x * blockDim.x + threadIdx.x;   // float4 chunk idx in batch
    int f0 = chunk * 4;
    if (f0 >= NF) return;
    size_t base = (size_t)b * NF;
    if (f0 >= K5) {
        float4 z = make_float4(0.f, 0.f, 0.f, 0.f);
        *(float4*)(out1 + base + f0) = z;
        *(float4*)(out2 + base + f0) = z;
    } else if (f0 + 4 > K5) {
        for (int j = K5; j < f0 + 4; ++j) {
            out1[base + j] = 0.0f;
            out2[base + j] = 0.0f;
        }
    }
}

extern "C" void kernel_launch(void* const* d_in, const int* in_sizes, int n_in,
                              void* d_out, int out_size, void* d_ws, size_t ws_size,
                              hipStream_t stream) {
    const float* cls = (const float*)d_in[0];   // [16,540,960,2]
    const float* roi = (const float*)d_in[1];   // [16,540,960,4]
    const float* img = (const float*)d_in[2];   // [16,2]

    float* out1 = (float*)d_out;                     // rect copy 1
    float* out2 = out1 + (size_t)NB * NF;            // rect copy 2
    float* outimg = out2 + (size_t)NB * NF;          // img + 1

    int* cnt    = (int*)d_ws;                        // [16][34][960]
    int* abase  = cnt + (size_t)NB * NCH * WW;       // [16][34][960]
    int* totals = abase + (size_t)NB * NCH * WW;     // [16]

    k_cnt<<<dim3(30, NCH, NB), dim3(256), 0, stream>>>((const float4*)cls, cnt);
    k_scan<<<dim3(NB), dim3(1024), 0, stream>>>(cnt, abase, totals, img, outimg);
    k_compact<<<dim3(60, NCH, NB), dim3(256), 0, stream>>>(cls, (const float4*)roi,
                                                           abase, out1, out2);
    k_ztail<<<dim3((NF / 4 + 255) / 256, NB), dim3(256), 0, stream>>>(totals, out1, out2);
}